// Round 4
// baseline (447.420 us; speedup 1.0000x reference)
//
#include <hip/hip_runtime.h>
#include <math.h>

#define HH 384
#define WW 384
#define CIN 32
#define HWP (HH*WW)   // 147456

// ws float offsets — total footprint identical to the verified rounds (xbf at 16384).
// Phase-1 (transform + early prep): ROWS, COLSH, GSUMH.
// Phase-2 (late prep + convfuse):  WBF, W2, CB alias the then-dead COLSH region.
#define WS_ROWS  0      // [plane][6] = 1536 raw row sums (rows 0,1,2,381,382,383), plain stores
#define WS_COLSH 1536   // [8 shard][256 plane][6] = 12288 col strip partials (atomic, memset 0)
#define WS_GSUMH 13824  // [8 shard][256 plane]    = 2048 gap partials (atomic, memset 0)
#define WS_WBF   1536   // 25*512 ushort = 6400 floats   (aliases COLSH; written after last COLSH read)
#define WS_W2    7936   // [b][c][co] = 4096              (aliases COLSH)
#define WS_CB    12032  // [b][co] = 256                  (aliases COLSH)
#define WS_XBF   16384  // bf16 x pixel-major: 8*147456*32 ushort

typedef __attribute__((ext_vector_type(8))) __bf16 bf16x8;
typedef __attribute__((ext_vector_type(4))) float  f32x4;

__device__ __forceinline__ unsigned bf16r(float f) {   // RNE fp32->bf16 bits
    unsigned u = __float_as_uint(f);
    return (u + 0x7fffu + ((u >> 16) & 1u)) >> 16;
}

__device__ __forceinline__ void softmax5(const float* attn, float sw[5]) {
    float a0=attn[0],a1=attn[1],a2=attn[2],a3=attn[3],a4=attn[4];
    float m = fmaxf(fmaxf(fmaxf(a0,a1),fmaxf(a2,a3)),a4);
    float e0=expf(a0-m),e1=expf(a1-m),e2=expf(a2-m),e3=expf(a3-m),e4=expf(a4-m);
    float inv = 1.f/(e0+e1+e2+e3+e4);
    sw[0]=e0*inv; sw[1]=e1*inv; sw[2]=e2*inv; sw[3]=e3*inv; sw[4]=e4*inv;
}

// ---------------- transform: NCHW fp32 -> pixel-major bf16 + sharded reductions ----------------
// 2 rows/block, float2/thread: 512B wave loads, 128B/thread contiguous stores (full-line
// write combine), half the shuffle count of the 1-px/thread version.
__global__ __launch_bounds__(384) void transform_kernel(const float* __restrict__ x,
        float* __restrict__ ws, unsigned short* __restrict__ xbf) {
    int blk = blockIdx.x;                 // 8 b * 192 row-pairs
    int b = blk / 192, rp = blk % 192;
    int t = threadIdx.x;                  // 384
    int rsub = t / 192;                   // 0: waves 0-2, 1: waves 3-5 (wave-uniform)
    int u = t % 192;
    int h = rp*2 + rsub;
    int w0 = u*2;
    const float* xp = x + (size_t)b*CIN*HWP + (size_t)h*WW + w0;

    __shared__ float red[32][49];         // [ch][48 partials + pad]
    int wv = t >> 6, ln = t & 63;
    int sh = blk & 7;
    // sub-column strip indices for w0 (x) and w0+1 (y)
    int jx = (w0 < 3) ? w0 : ((w0 >= 381) ? w0 - 378 : -1);
    int c1 = w0 + 1;
    int jy = (c1 < 3) ? c1 : ((c1 >= 381) ? c1 - 378 : -1);

    unsigned uu0[16], uu1[16];            // px w0, px w0+1
    #pragma unroll
    for (int ck = 0; ck < 4; ++ck) {
        float2 v[8];
        #pragma unroll
        for (int j = 0; j < 8; ++j)
            v[j] = *(const float2*)(xp + (size_t)(ck*8 + j)*HWP);

        #pragma unroll
        for (int k = 0; k < 4; ++k) {
            uu0[ck*4 + k] = bf16r(v[2*k].x) | (bf16r(v[2*k+1].x) << 16);
            uu1[ck*4 + k] = bf16r(v[2*k].y) | (bf16r(v[2*k+1].y) << 16);
        }

        if (jx >= 0 || jy >= 0) {
            #pragma unroll
            for (int j = 0; j < 8; ++j) {
                int pl = (b*32 + ck*8 + j)*6;
                if (jx >= 0) atomicAdd(&ws[WS_COLSH + sh*1536 + pl + jx], v[j].x);
                if (jy >= 0) atomicAdd(&ws[WS_COLSH + sh*1536 + pl + jy], v[j].y);
            }
        }

        #pragma unroll
        for (int j = 0; j < 8; ++j) {
            float s = v[j].x + v[j].y;
            s += __shfl_down(s, 32);
            s += __shfl_down(s, 16);
            s += __shfl_down(s, 8);
            if (ln < 8) red[ck*8 + j][wv*8 + ln] = s;
        }
    }

    // 128 B contiguous store per thread (2 pixels x 64 B), lanes consecutive
    uint4* dst = (uint4*)(xbf + ((size_t)b*HWP + (size_t)h*WW + w0)*32);
    dst[0] = make_uint4(uu0[0],  uu0[1],  uu0[2],  uu0[3]);
    dst[1] = make_uint4(uu0[4],  uu0[5],  uu0[6],  uu0[7]);
    dst[2] = make_uint4(uu0[8],  uu0[9],  uu0[10], uu0[11]);
    dst[3] = make_uint4(uu0[12], uu0[13], uu0[14], uu0[15]);
    dst[4] = make_uint4(uu1[0],  uu1[1],  uu1[2],  uu1[3]);
    dst[5] = make_uint4(uu1[4],  uu1[5],  uu1[6],  uu1[7]);
    dst[6] = make_uint4(uu1[8],  uu1[9],  uu1[10], uu1[11]);
    dst[7] = make_uint4(uu1[12], uu1[13], uu1[14], uu1[15]);

    __syncthreads();
    if (t < 32) {
        // waves 0-2 (partials 0..23) = row rp*2; waves 3-5 (24..47) = row rp*2+1
        float rsumA = 0.f, rsumB = 0.f;
        #pragma unroll
        for (int i = 0; i < 24; ++i) { rsumA += red[t][i]; rsumB += red[t][24 + i]; }
        atomicAdd(&ws[WS_GSUMH + sh*256 + b*32 + t], rsumA + rsumB);
        int h0 = rp*2, h1 = h0 + 1;
        int rj0 = (h0 < 3) ? h0 : ((h0 >= 381) ? h0 - 378 : -1);
        int rj1 = (h1 < 3) ? h1 : ((h1 >= 381) ? h1 - 378 : -1);
        if (rj0 >= 0) ws[WS_ROWS + (b*32 + t)*6 + rj0] = rsumA;
        if (rj1 >= 0) ws[WS_ROWS + (b*32 + t)*6 + rj1] = rsumB;
    }
}

// ---------------- prep: corners, f5, taps, node feats, GCN, W2, CB ----------------
__device__ __forceinline__ float rectsum(const float* bd, float T, int dh, int dw) {
    int r0 = dh > 0 ?  dh : 0, b0 = dh < 0 ? -dh : 0;
    int c0 = dw > 0 ?  dw : 0, d0 = dw < 0 ? -dw : 0;
    float v = T;
    if (r0) v -= bd[r0-1];
    if (b0) v -= bd[3+b0-1];
    if (c0) v -= bd[6+c0-1];
    if (d0) v -= bd[9+d0-1];
    if (r0 && c0) v += bd[12+(r0-1)*3+(c0-1)];
    if (r0 && d0) v += bd[21+(r0-1)*3+(d0-1)];
    if (b0 && c0) v += bd[30+(b0-1)*3+(c0-1)];
    if (b0 && d0) v += bd[39+(b0-1)*3+(d0-1)];
    return v;
}

__global__ void prep_kernel(const float* __restrict__ x,
                            const float* __restrict__ w1, const float* __restrict__ b1,
                            const float* __restrict__ w2, const float* __restrict__ b2,
                            const float* __restrict__ w3, const float* __restrict__ b3,
                            const float* __restrict__ w4, const float* __restrict__ b4,
                            const float* __restrict__ w5, const float* __restrict__ b5,
                            const float* __restrict__ gcn_w, const float* __restrict__ gcn_b,
                            const float* __restrict__ fusion_w, const float* __restrict__ fusion_b,
                            const float* __restrict__ attn, float* __restrict__ ws) {
    __shared__ float srect[256*28];     // 27 rect-sums per plane (pad to 28)
    __shared__ float gsum_s[256];
    __shared__ float sacc[128][4];      // per (b,c): sum w1*T, s2, s3, s4
    __shared__ float ns[128], bbf[128], gl[128];
    float sw[5];
    softmax5(attn, sw);
    int t = threadIdx.x;   // 256
    const float invHW = 1.f / (float)HWP;

    // top: reduce gsum shards into LDS
    {
        float g = 0.f;
        #pragma unroll
        for (int s = 0; s < 8; ++s) g += ws[WS_GSUMH + s*256 + t];
        gsum_s[t] = g;
    }
    __syncthreads();

    // A: per-plane bd table in registers -> 27 rect-sums into LDS (computed ONCE per plane)
    {
        int plane = t;
        float bd[48];
        const float* rw = ws + WS_ROWS + plane*6;
        float cl[6];
        #pragma unroll
        for (int j = 0; j < 6; ++j) {
            float s = 0.f;
            #pragma unroll
            for (int sh = 0; sh < 8; ++sh) s += ws[WS_COLSH + sh*1536 + plane*6 + j];
            cl[j] = s;
        }
        bd[0]=rw[0]; bd[1]=rw[0]+rw[1]; bd[2]=rw[0]+rw[1]+rw[2];
        bd[3]=rw[5]; bd[4]=rw[5]+rw[4]; bd[5]=rw[5]+rw[4]+rw[3];
        bd[6]=cl[0]; bd[7]=cl[0]+cl[1]; bd[8]=cl[0]+cl[1]+cl[2];
        bd[9]=cl[5]; bd[10]=cl[5]+cl[4]; bd[11]=cl[5]+cl[4]+cl[3];
        const float* xp = x + (size_t)plane*HWP;
        for (int a = 1; a <= 3; ++a)
        for (int bb = 1; bb <= 3; ++bb) {
            float tl=0,tr=0,bl=0,br=0;
            for (int h = 0; h < a; ++h)
            for (int w = 0; w < bb; ++w) {
                tl += xp[h*WW + w];
                tr += xp[h*WW + (WW-1-w)];
                bl += xp[(HH-1-h)*WW + w];
                br += xp[(HH-1-h)*WW + (WW-1-w)];
            }
            int o = (a-1)*3 + (bb-1);
            bd[12+o]=tl; bd[21+o]=tr; bd[30+o]=bl; bd[39+o]=br;
        }
        float T = gsum_s[plane];
        float* rp = srect + plane*28;
        #pragma unroll
        for (int d = 0; d < 3; ++d)
        #pragma unroll
        for (int kk = 0; kk < 9; ++kk)
            rp[d*9 + kk] = rectsum(bd, T, (kk/3 - 1)*(d+1), (kk%3 - 1)*(d+1));
        if (t < 128) { sacc[t][0]=0.f; sacc[t][1]=0.f; sacc[t][2]=0.f; sacc[t][3]=0.f; }
    }
    // COLSH is dead from here on; WBF/W2/CB alias it. Must fence ALL threads' A-reads
    // before any B-write lands.
    __syncthreads();

    // B: f5 (kept in register) + bf16 merged taps
    float f5v = 0.f;
    if (t < 128) {
        int b = t >> 4, c = t & 15;
        f5v = b5[c];
        for (int ci = 0; ci < CIN; ++ci)
            f5v += w5[c*CIN+ci] * gsum_s[b*32 + ci] * invHW;
    }
    {
        unsigned short* wbf = (unsigned short*)(ws + WS_WBF);
        const int tk[8] = {0,1,2,3,5,6,7,8};
        for (int idx = t; idx < 25*512; idx += blockDim.x) {
            int tap  = idx >> 9;
            int lane = (idx >> 3) & 63;
            int j    = idx & 7;
            int cin  = ((lane >> 4) << 3) | j;
            int c    = lane & 15;
            float v;
            if (tap == 0) {
                v = sw[0]*w1[c*CIN+cin]
                  + sw[1]*w2[c*288 + cin*9 + 4]
                  + sw[2]*w3[c*288 + cin*9 + 4]
                  + sw[3]*w4[c*288 + cin*9 + 4];
            } else {
                int g = (tap-1) >> 3;
                int mth = (tap-1) & 7;
                int kk = tk[mth];
                const float* w = (g == 0) ? w2 : ((g == 1) ? w3 : w4);
                v = sw[g+1] * w[c*288 + cin*9 + kk];
            }
            wbf[idx] = (unsigned short)bf16r(v);
        }
    }
    __syncthreads();   // srect + sacc-zero ready

    // C1: all 256 threads: (c, 2 cins) each, dot weights with shared rect-sums
    {
        int c = t & 15, cing = t >> 4;   // cing 0..15, cins {2cing, 2cing+1}
        float w1t[2], w2t[2][9], w3t[2][9], w4t[2][9];
        #pragma unroll
        for (int i = 0; i < 2; ++i) {
            int cin = cing*2 + i;
            w1t[i] = w1[c*CIN + cin];
            #pragma unroll
            for (int kk = 0; kk < 9; ++kk) {
                w2t[i][kk] = w2[c*288 + cin*9 + kk];
                w3t[i][kk] = w3[c*288 + cin*9 + kk];
                w4t[i][kk] = w4[c*288 + cin*9 + kk];
            }
        }
        #pragma unroll
        for (int b = 0; b < 8; ++b) {
            float a1 = 0.f, a2 = 0.f, a3 = 0.f, a4 = 0.f;
            #pragma unroll
            for (int i = 0; i < 2; ++i) {
                int plane = b*32 + cing*2 + i;
                const float* rp = srect + plane*28;
                a1 += w1t[i] * gsum_s[plane];
                #pragma unroll
                for (int kk = 0; kk < 9; ++kk) {
                    a2 += w2t[i][kk] * rp[kk];
                    a3 += w3t[i][kk] * rp[9 + kk];
                    a4 += w4t[i][kk] * rp[18 + kk];
                }
            }
            atomicAdd(&sacc[b*16 + c][0], a1);
            atomicAdd(&sacc[b*16 + c][1], a2);
            atomicAdd(&sacc[b*16 + c][2], a3);
            atomicAdd(&sacc[b*16 + c][3], a4);
        }
    }
    __syncthreads();

    // C2: node feats
    if (t < 128) {
        int c = t & 15;
        float nf1 = b1[c] + sacc[t][0]*invHW;
        float nf2 = b2[c] + sacc[t][1]*invHW;
        float nf3 = b3[c] + sacc[t][2]*invHW;
        float nf4 = b4[c] + sacc[t][3]*invHW;
        ns[t]  = 0.2f * (nf1 + nf2 + nf3 + nf4 + f5v);
        bbf[t] = sw[0]*b1[c] + sw[1]*b2[c] + sw[2]*b3[c] + sw[3]*b4[c] + sw[4]*f5v;
    }
    __syncthreads();
    if (t < 128) {
        int b = t >> 4, c = t & 15;
        float acc = gcn_b[c];
        for (int k = 0; k < 16; ++k) acc += ns[b*16 + k] * gcn_w[k*16 + c];
        gl[t] = acc;
    }
    __syncthreads();
    for (int idx = t; idx < 4096; idx += blockDim.x) {
        int b = idx >> 9, c = (idx >> 5) & 15, co = idx & 31;
        ws[WS_W2 + idx] = fusion_w[co*16 + c] * gl[b*16 + c];
    }
    {
        int b = t >> 5, co = t & 31;
        float acc = fusion_b[co];
        for (int c = 0; c < 16; ++c)
            acc += fusion_w[co*16 + c] * gl[b*16 + c] * bbf[b*16 + c];
        ws[WS_CB + t] = acc;
    }
}

// ---------------- convfuse: MFMA conv + fused 16->32 mix, writes out directly ----------------
__global__ __launch_bounds__(256) void convfuse_kernel(
        const unsigned short* __restrict__ xbf, const unsigned short* __restrict__ wBf,
        const float* __restrict__ ws_ro, float* __restrict__ out) {
    __shared__ __align__(16) char smem[40896];
    unsigned short* sx = (unsigned short*)smem;        // [484 pix][40 bf16]
    float* w2s = (float*)(smem + 38720);               // 512 f
    float* cbs = (float*)(smem + 40768);               // 32 f
    int blk = blockIdx.x;
    int b = blk / 576, tno = blk % 576;
    int h0 = (tno / 24) * 16, w0 = (tno % 24) * 16;
    int tid = threadIdx.x;

    w2s[tid]       = ws_ro[WS_W2 + b*512 + tid];
    w2s[tid + 256] = ws_ro[WS_W2 + b*512 + 256 + tid];
    if (tid < 32) cbs[tid] = ws_ro[WS_CB + b*32 + tid];

    // stage bf16 halo pixels (64 B contiguous each)
    for (int p = tid; p < 484; p += 256) {
        int r = p / 22, c = p - r*22;
        int gh = h0 - 3 + r, gw = w0 - 3 + c;
        uint4 a0 = {0,0,0,0}, a1 = a0, a2 = a0, a3 = a0;
        if ((unsigned)gh < (unsigned)HH && (unsigned)gw < (unsigned)WW) {
            const uint4* src = (const uint4*)(xbf + ((size_t)b*HWP + (size_t)gh*WW + gw)*32);
            a0 = src[0]; a1 = src[1]; a2 = src[2]; a3 = src[3];
        }
        uint4* d = (uint4*)(sx + p*40);
        d[0] = a0; d[1] = a1; d[2] = a2; d[3] = a3;
    }
    __syncthreads();

    int lane = tid & 63, wv = tid >> 6;
    int m = lane & 15, q = lane >> 4;
    int by0 = ((wv*4 + 0 + 3)*22 + 3 + m)*40 + q*8;
    int by1 = by0 + 22*40;
    int by2 = by1 + 22*40;
    int by3 = by2 + 22*40;
    const unsigned short* wfp = wBf + lane*8;

    f32x4 acc0 = {0.f,0.f,0.f,0.f}, acc1 = {0.f,0.f,0.f,0.f};
    f32x4 acc2 = {0.f,0.f,0.f,0.f}, acc3 = {0.f,0.f,0.f,0.f};

    constexpr int TDH[25] = {0, -1,-1,-1,0,0,1,1,1, -2,-2,-2,0,0,2,2,2, -3,-3,-3,0,0,3,3,3};
    constexpr int TDW[25] = {0, -1,0,1,-1,1,-1,0,1, -2,0,2,-2,2,-2,0,2, -3,0,3,-3,3,-3,0,3};
    #pragma unroll
    for (int tap = 0; tap < 25; ++tap) {
        bf16x8 bw = *(const bf16x8*)(wfp + tap*512);
        const int to = (TDH[tap]*22 + TDW[tap])*40;
        acc0 = __builtin_amdgcn_mfma_f32_16x16x32_bf16(*(const bf16x8*)(sx + by0 + to), bw, acc0, 0, 0, 0);
        acc1 = __builtin_amdgcn_mfma_f32_16x16x32_bf16(*(const bf16x8*)(sx + by1 + to), bw, acc1, 0, 0, 0);
        acc2 = __builtin_amdgcn_mfma_f32_16x16x32_bf16(*(const bf16x8*)(sx + by2 + to), bw, acc2, 0, 0, 0);
        acc3 = __builtin_amdgcn_mfma_f32_16x16x32_bf16(*(const bf16x8*)(sx + by3 + to), bw, acc3, 0, 0, 0);
    }
    __syncthreads();   // done reading sx; reuse as fp32 S-tile

    // transpose acc through LDS: st[pix(256)][c] stride 17
    float* st = (float*)smem;
    #pragma unroll
    for (int g2 = 0; g2 < 4; ++g2) {
        int y = wv*4 + g2;
        f32x4 a = (g2 == 0) ? acc0 : (g2 == 1) ? acc1 : (g2 == 2) ? acc2 : acc3;
        #pragma unroll
        for (int r = 0; r < 4; ++r) {
            int px = q*4 + r;
            st[(y*16 + px)*17 + m] = a[r];
        }
    }
    __syncthreads();

    // per-thread pixel: 16 -> 32 mix + store (non-temporal: out never re-read)
    float sv[16];
    #pragma unroll
    for (int c = 0; c < 16; ++c) sv[c] = st[tid*17 + c];
    float acc[32];
    #pragma unroll
    for (int co = 0; co < 32; ++co) acc[co] = cbs[co];
    #pragma unroll
    for (int c = 0; c < 16; ++c) {
        float v = sv[c];
        #pragma unroll
        for (int co = 0; co < 32; ++co) acc[co] = fmaf(w2s[c*32 + co], v, acc[co]);
    }
    int y = tid >> 4, px = tid & 15;
    float* ob = out + (size_t)b*32*HWP + (size_t)(h0 + y)*WW + w0 + px;
    #pragma unroll
    for (int co = 0; co < 32; ++co)
        __builtin_nontemporal_store(acc[co], &ob[(size_t)co * HWP]);
}

extern "C" void kernel_launch(void* const* d_in, const int* in_sizes, int n_in,
                              void* d_out, int out_size, void* d_ws, size_t ws_size,
                              hipStream_t stream) {
    const float* x     = (const float*)d_in[0];
    const float* w1    = (const float*)d_in[1];  const float* b1 = (const float*)d_in[2];
    const float* w2    = (const float*)d_in[3];  const float* b2 = (const float*)d_in[4];
    const float* w3    = (const float*)d_in[5];  const float* b3 = (const float*)d_in[6];
    const float* w4    = (const float*)d_in[7];  const float* b4 = (const float*)d_in[8];
    const float* w5    = (const float*)d_in[9];  const float* b5 = (const float*)d_in[10];
    const float* gcn_w = (const float*)d_in[11]; const float* gcn_b = (const float*)d_in[12];
    const float* attn  = (const float*)d_in[13];
    const float* fw    = (const float*)d_in[14]; const float* fb = (const float*)d_in[15];
    float* ws  = (float*)d_ws;
    float* out = (float*)d_out;
    unsigned short* xbf = (unsigned short*)(ws + WS_XBF);

    // zero the sharded accumulators [WS_COLSH, WS_GSUMH end)
    hipMemsetAsync(ws + WS_COLSH, 0, (15872 - WS_COLSH) * sizeof(float), stream);
    transform_kernel<<<8*192, 384, 0, stream>>>(x, ws, xbf);
    prep_kernel     <<<1, 256, 0, stream>>>(x, w1,b1,w2,b2,w3,b3,w4,b4,w5,b5,
                                            gcn_w, gcn_b, fw, fb, attn, ws);
    convfuse_kernel <<<4608, 256, 0, stream>>>(xbf, (const unsigned short*)(ws + WS_WBF), ws, out);
}

// Round 5
// 394.028 us; speedup vs baseline: 1.1355x; 1.1355x over previous
//
#include <hip/hip_runtime.h>
#include <math.h>

#define HH 384
#define WW 384
#define CIN 32
#define HWP (HH*WW)   // 147456

// ws float offsets — total footprint identical to the verified rounds (xbf at 16384).
// Phase-1 (transform + early prep): ROWS, COLSH, GSUMH.
// Phase-2 (late prep + convfuse):  WBF, W2, CB alias the then-dead COLSH region.
#define WS_ROWS  0      // [plane][6] = 1536 raw row sums (rows 0,1,2,381,382,383), plain stores
#define WS_COLSH 1536   // [8 shard][256 plane][6] = 12288 col strip partials (atomic, memset 0)
#define WS_GSUMH 13824  // [8 shard][256 plane]    = 2048 gap partials (atomic, memset 0)
#define WS_WBF   1536   // 25*512 ushort = 6400 floats   (aliases COLSH; written after last COLSH read)
#define WS_W2    7936   // [b][c][co] = 4096              (aliases COLSH)
#define WS_CB    12032  // [b][co] = 256                  (aliases COLSH)
#define WS_XBF   16384  // bf16 x pixel-major: 8*147456*32 ushort

typedef __attribute__((ext_vector_type(8))) __bf16 bf16x8;
typedef __attribute__((ext_vector_type(4))) float  f32x4;
typedef __attribute__((ext_vector_type(2))) float  f32x2;

__device__ __forceinline__ unsigned bf16r(float f) {   // RNE fp32->bf16 bits
    unsigned u = __float_as_uint(f);
    return (u + 0x7fffu + ((u >> 16) & 1u)) >> 16;
}

__device__ __forceinline__ void softmax5(const float* attn, float sw[5]) {
    float a0=attn[0],a1=attn[1],a2=attn[2],a3=attn[3],a4=attn[4];
    float m = fmaxf(fmaxf(fmaxf(a0,a1),fmaxf(a2,a3)),a4);
    float e0=expf(a0-m),e1=expf(a1-m),e2=expf(a2-m),e3=expf(a3-m),e4=expf(a4-m);
    float inv = 1.f/(e0+e1+e2+e3+e4);
    sw[0]=e0*inv; sw[1]=e1*inv; sw[2]=e2*inv; sw[3]=e3*inv; sw[4]=e4*inv;
}

// ---------------- transform: NCHW fp32 -> pixel-major bf16 + sharded reductions ----------------
// (round-3 verified version: 1 px/thread, chunked 8-ch loads for bounded live regs,
//  full 64B reg-buffered store, atomics sharded 8x by h&7. Latency-bound: thread
//  count beats per-lane width here — 2px/thread variant halved occupancy and regressed.)
__global__ __launch_bounds__(384) void transform_kernel(const float* __restrict__ x,
        float* __restrict__ ws, unsigned short* __restrict__ xbf) {
    int b = blockIdx.x / HH, h = blockIdx.x % HH;
    int t = threadIdx.x;   // = w
    const float* xp = x + (size_t)b*CIN*HWP + (size_t)h*WW + t;

    __shared__ float red[32][49];
    int wv = t >> 6, ln = t & 63;
    int cj = (t < 3) ? t : ((t >= 381) ? t - 378 : -1);
    int sh = h & 7;

    unsigned uu[16];
    #pragma unroll
    for (int ck = 0; ck < 4; ++ck) {
        float v[8];
        #pragma unroll
        for (int j = 0; j < 8; ++j) v[j] = xp[(size_t)(ck*8 + j)*HWP];

        #pragma unroll
        for (int k = 0; k < 4; ++k) uu[ck*4 + k] = bf16r(v[2*k]) | (bf16r(v[2*k+1]) << 16);

        if (cj >= 0) {
            #pragma unroll
            for (int j = 0; j < 8; ++j)
                atomicAdd(&ws[WS_COLSH + (sh*256 + b*32 + ck*8 + j)*6 + cj], v[j]);
        }

        #pragma unroll
        for (int j = 0; j < 8; ++j) {
            float s = v[j];
            s += __shfl_down(s, 32);
            s += __shfl_down(s, 16);
            s += __shfl_down(s, 8);
            if (ln < 8) red[ck*8 + j][wv*8 + ln] = s;
        }
    }

    // contiguous 64B store per pixel (write-combines to full lines)
    uint4* dst = (uint4*)(xbf + ((size_t)b*HWP + (size_t)h*WW + t)*32);
    dst[0] = make_uint4(uu[0], uu[1], uu[2], uu[3]);
    dst[1] = make_uint4(uu[4], uu[5], uu[6], uu[7]);
    dst[2] = make_uint4(uu[8], uu[9], uu[10], uu[11]);
    dst[3] = make_uint4(uu[12], uu[13], uu[14], uu[15]);

    __syncthreads();
    if (t < 32) {
        float rsum = 0.f;
        #pragma unroll
        for (int i = 0; i < 48; ++i) rsum += red[t][i];
        atomicAdd(&ws[WS_GSUMH + sh*256 + b*32 + t], rsum);
        int rj = (h < 3) ? h : ((h >= 381) ? h - 378 : -1);
        if (rj >= 0) ws[WS_ROWS + (b*32 + t)*6 + rj] = rsum;
    }
}

// ---------------- prep: corners, f5, taps, node feats, GCN, W2, CB ----------------
__device__ __forceinline__ float rectsum(const float* bd, float T, int dh, int dw) {
    int r0 = dh > 0 ?  dh : 0, b0 = dh < 0 ? -dh : 0;
    int c0 = dw > 0 ?  dw : 0, d0 = dw < 0 ? -dw : 0;
    float v = T;
    if (r0) v -= bd[r0-1];
    if (b0) v -= bd[3+b0-1];
    if (c0) v -= bd[6+c0-1];
    if (d0) v -= bd[9+d0-1];
    if (r0 && c0) v += bd[12+(r0-1)*3+(c0-1)];
    if (r0 && d0) v += bd[21+(r0-1)*3+(d0-1)];
    if (b0 && c0) v += bd[30+(b0-1)*3+(c0-1)];
    if (b0 && d0) v += bd[39+(b0-1)*3+(d0-1)];
    return v;
}

__global__ void prep_kernel(const float* __restrict__ x,
                            const float* __restrict__ w1, const float* __restrict__ b1,
                            const float* __restrict__ w2, const float* __restrict__ b2,
                            const float* __restrict__ w3, const float* __restrict__ b3,
                            const float* __restrict__ w4, const float* __restrict__ b4,
                            const float* __restrict__ w5, const float* __restrict__ b5,
                            const float* __restrict__ gcn_w, const float* __restrict__ gcn_b,
                            const float* __restrict__ fusion_w, const float* __restrict__ fusion_b,
                            const float* __restrict__ attn, float* __restrict__ ws) {
    __shared__ float srect[256*28];     // 27 rect-sums per plane (pad to 28)
    __shared__ float gsum_s[256];
    __shared__ float sacc[128][4];      // per (b,c): sum w1*T, s2, s3, s4
    __shared__ float ns[128], bbf[128], gl[128];
    float sw[5];
    softmax5(attn, sw);
    int t = threadIdx.x;   // 256
    const float invHW = 1.f / (float)HWP;

    // top: reduce gsum shards into LDS
    {
        float g = 0.f;
        #pragma unroll
        for (int s = 0; s < 8; ++s) g += ws[WS_GSUMH + s*256 + t];
        gsum_s[t] = g;
    }
    __syncthreads();

    // A: per-plane bd table in registers -> 27 rect-sums into LDS (computed ONCE per plane)
    {
        int plane = t;
        float bd[48];
        const float* rw = ws + WS_ROWS + plane*6;
        float cl[6];
        #pragma unroll
        for (int j = 0; j < 6; ++j) {
            float s = 0.f;
            #pragma unroll
            for (int sh = 0; sh < 8; ++sh) s += ws[WS_COLSH + (sh*256 + plane)*6 + j];
            cl[j] = s;
        }
        bd[0]=rw[0]; bd[1]=rw[0]+rw[1]; bd[2]=rw[0]+rw[1]+rw[2];
        bd[3]=rw[5]; bd[4]=rw[5]+rw[4]; bd[5]=rw[5]+rw[4]+rw[3];
        bd[6]=cl[0]; bd[7]=cl[0]+cl[1]; bd[8]=cl[0]+cl[1]+cl[2];
        bd[9]=cl[5]; bd[10]=cl[5]+cl[4]; bd[11]=cl[5]+cl[4]+cl[3];
        const float* xp = x + (size_t)plane*HWP;
        for (int a = 1; a <= 3; ++a)
        for (int bb = 1; bb <= 3; ++bb) {
            float tl=0,tr=0,bl=0,br=0;
            for (int h = 0; h < a; ++h)
            for (int w = 0; w < bb; ++w) {
                tl += xp[h*WW + w];
                tr += xp[h*WW + (WW-1-w)];
                bl += xp[(HH-1-h)*WW + w];
                br += xp[(HH-1-h)*WW + (WW-1-w)];
            }
            int o = (a-1)*3 + (bb-1);
            bd[12+o]=tl; bd[21+o]=tr; bd[30+o]=bl; bd[39+o]=br;
        }
        float T = gsum_s[plane];
        float* rp = srect + plane*28;
        #pragma unroll
        for (int d = 0; d < 3; ++d)
        #pragma unroll
        for (int kk = 0; kk < 9; ++kk)
            rp[d*9 + kk] = rectsum(bd, T, (kk/3 - 1)*(d+1), (kk%3 - 1)*(d+1));
        if (t < 128) { sacc[t][0]=0.f; sacc[t][1]=0.f; sacc[t][2]=0.f; sacc[t][3]=0.f; }
    }
    // COLSH is dead from here on; WBF/W2/CB alias it. Must fence ALL threads' A-reads
    // before any B-write lands.
    __syncthreads();

    // B: f5 (kept in register) + bf16 merged taps
    float f5v = 0.f;
    if (t < 128) {
        int b = t >> 4, c = t & 15;
        f5v = b5[c];
        for (int ci = 0; ci < CIN; ++ci)
            f5v += w5[c*CIN+ci] * gsum_s[b*32 + ci] * invHW;
    }
    {
        unsigned short* wbf = (unsigned short*)(ws + WS_WBF);
        const int tk[8] = {0,1,2,3,5,6,7,8};
        for (int idx = t; idx < 25*512; idx += blockDim.x) {
            int tap  = idx >> 9;
            int lane = (idx >> 3) & 63;
            int j    = idx & 7;
            int cin  = ((lane >> 4) << 3) | j;
            int c    = lane & 15;
            float v;
            if (tap == 0) {
                v = sw[0]*w1[c*CIN+cin]
                  + sw[1]*w2[c*288 + cin*9 + 4]
                  + sw[2]*w3[c*288 + cin*9 + 4]
                  + sw[3]*w4[c*288 + cin*9 + 4];
            } else {
                int g = (tap-1) >> 3;
                int mth = (tap-1) & 7;
                int kk = tk[mth];
                const float* w = (g == 0) ? w2 : ((g == 1) ? w3 : w4);
                v = sw[g+1] * w[c*288 + cin*9 + kk];
            }
            wbf[idx] = (unsigned short)bf16r(v);
        }
    }
    __syncthreads();   // srect + sacc-zero ready

    // C1: all 256 threads: (c, 2 cins) each, dot weights with shared rect-sums
    {
        int c = t & 15, cing = t >> 4;   // cing 0..15, cins {2cing, 2cing+1}
        float w1t[2], w2t[2][9], w3t[2][9], w4t[2][9];
        #pragma unroll
        for (int i = 0; i < 2; ++i) {
            int cin = cing*2 + i;
            w1t[i] = w1[c*CIN + cin];
            #pragma unroll
            for (int kk = 0; kk < 9; ++kk) {
                w2t[i][kk] = w2[c*288 + cin*9 + kk];
                w3t[i][kk] = w3[c*288 + cin*9 + kk];
                w4t[i][kk] = w4[c*288 + cin*9 + kk];
            }
        }
        #pragma unroll
        for (int b = 0; b < 8; ++b) {
            float a1 = 0.f, a2 = 0.f, a3 = 0.f, a4 = 0.f;
            #pragma unroll
            for (int i = 0; i < 2; ++i) {
                int plane = b*32 + cing*2 + i;
                const float* rp = srect + plane*28;
                a1 += w1t[i] * gsum_s[plane];
                #pragma unroll
                for (int kk = 0; kk < 9; ++kk) {
                    a2 += w2t[i][kk] * rp[kk];
                    a3 += w3t[i][kk] * rp[9 + kk];
                    a4 += w4t[i][kk] * rp[18 + kk];
                }
            }
            atomicAdd(&sacc[b*16 + c][0], a1);
            atomicAdd(&sacc[b*16 + c][1], a2);
            atomicAdd(&sacc[b*16 + c][2], a3);
            atomicAdd(&sacc[b*16 + c][3], a4);
        }
    }
    __syncthreads();

    // C2: node feats
    if (t < 128) {
        int c = t & 15;
        float nf1 = b1[c] + sacc[t][0]*invHW;
        float nf2 = b2[c] + sacc[t][1]*invHW;
        float nf3 = b3[c] + sacc[t][2]*invHW;
        float nf4 = b4[c] + sacc[t][3]*invHW;
        ns[t]  = 0.2f * (nf1 + nf2 + nf3 + nf4 + f5v);
        bbf[t] = sw[0]*b1[c] + sw[1]*b2[c] + sw[2]*b3[c] + sw[3]*b4[c] + sw[4]*f5v;
    }
    __syncthreads();
    if (t < 128) {
        int b = t >> 4, c = t & 15;
        float acc = gcn_b[c];
        for (int k = 0; k < 16; ++k) acc += ns[b*16 + k] * gcn_w[k*16 + c];
        gl[t] = acc;
    }
    __syncthreads();
    for (int idx = t; idx < 4096; idx += blockDim.x) {
        int b = idx >> 9, c = (idx >> 5) & 15, co = idx & 31;
        ws[WS_W2 + idx] = fusion_w[co*16 + c] * gl[b*16 + c];
    }
    {
        int b = t >> 5, co = t & 31;
        float acc = fusion_b[co];
        for (int c = 0; c < 16; ++c)
            acc += fusion_w[co*16 + c] * gl[b*16 + c] * bbf[b*16 + c];
        ws[WS_CB + t] = acc;
    }
}

// ---------------- convfuse: MFMA conv + fused 16->32 mix, writes out directly ----------------
__global__ __launch_bounds__(256) void convfuse_kernel(
        const unsigned short* __restrict__ xbf, const unsigned short* __restrict__ wBf,
        const float* __restrict__ ws_ro, float* __restrict__ out) {
    __shared__ __align__(16) char smem[40896];
    unsigned short* sx = (unsigned short*)smem;        // [484 pix][40 bf16]
    float* w2s = (float*)(smem + 38720);               // 512 f
    float* cbs = (float*)(smem + 40768);               // 32 f
    int blk = blockIdx.x;
    int b = blk / 576, tno = blk % 576;
    int h0 = (tno / 24) * 16, w0 = (tno % 24) * 16;
    int tid = threadIdx.x;

    w2s[tid]       = ws_ro[WS_W2 + b*512 + tid];
    w2s[tid + 256] = ws_ro[WS_W2 + b*512 + 256 + tid];
    if (tid < 32) cbs[tid] = ws_ro[WS_CB + b*32 + tid];

    // stage bf16 halo pixels (64 B contiguous each)
    for (int p = tid; p < 484; p += 256) {
        int r = p / 22, c = p - r*22;
        int gh = h0 - 3 + r, gw = w0 - 3 + c;
        uint4 a0 = {0,0,0,0}, a1 = a0, a2 = a0, a3 = a0;
        if ((unsigned)gh < (unsigned)HH && (unsigned)gw < (unsigned)WW) {
            const uint4* src = (const uint4*)(xbf + ((size_t)b*HWP + (size_t)gh*WW + gw)*32);
            a0 = src[0]; a1 = src[1]; a2 = src[2]; a3 = src[3];
        }
        uint4* d = (uint4*)(sx + p*40);
        d[0] = a0; d[1] = a1; d[2] = a2; d[3] = a3;
    }
    __syncthreads();

    int lane = tid & 63, wv = tid >> 6;
    int m = lane & 15, q = lane >> 4;
    int by0 = ((wv*4 + 0 + 3)*22 + 3 + m)*40 + q*8;
    int by1 = by0 + 22*40;
    int by2 = by1 + 22*40;
    int by3 = by2 + 22*40;
    const unsigned short* wfp = wBf + lane*8;

    f32x4 acc0 = {0.f,0.f,0.f,0.f}, acc1 = {0.f,0.f,0.f,0.f};
    f32x4 acc2 = {0.f,0.f,0.f,0.f}, acc3 = {0.f,0.f,0.f,0.f};

    constexpr int TDH[25] = {0, -1,-1,-1,0,0,1,1,1, -2,-2,-2,0,0,2,2,2, -3,-3,-3,0,0,3,3,3};
    constexpr int TDW[25] = {0, -1,0,1,-1,1,-1,0,1, -2,0,2,-2,2,-2,0,2, -3,0,3,-3,3,-3,0,3};
    #pragma unroll
    for (int tap = 0; tap < 25; ++tap) {
        bf16x8 bw = *(const bf16x8*)(wfp + tap*512);
        const int to = (TDH[tap]*22 + TDW[tap])*40;
        acc0 = __builtin_amdgcn_mfma_f32_16x16x32_bf16(*(const bf16x8*)(sx + by0 + to), bw, acc0, 0, 0, 0);
        acc1 = __builtin_amdgcn_mfma_f32_16x16x32_bf16(*(const bf16x8*)(sx + by1 + to), bw, acc1, 0, 0, 0);
        acc2 = __builtin_amdgcn_mfma_f32_16x16x32_bf16(*(const bf16x8*)(sx + by2 + to), bw, acc2, 0, 0, 0);
        acc3 = __builtin_amdgcn_mfma_f32_16x16x32_bf16(*(const bf16x8*)(sx + by3 + to), bw, acc3, 0, 0, 0);
    }
    __syncthreads();   // done reading sx; reuse as fp32 S-tile

    // transpose acc through LDS: st[pix(256)][c] stride 20 (16B-aligned rows -> b128 reads;
    // write banks (16q+m)%32 = 2 lanes/bank = free; read starts 20*tid%32 cycle-8 = uniform)
    float* st = (float*)smem;
    #pragma unroll
    for (int g2 = 0; g2 < 4; ++g2) {
        int y = wv*4 + g2;
        f32x4 a = (g2 == 0) ? acc0 : (g2 == 1) ? acc1 : (g2 == 2) ? acc2 : acc3;
        #pragma unroll
        for (int r = 0; r < 4; ++r) {
            int px = q*4 + r;
            st[(y*16 + px)*20 + m] = a[r];
        }
    }
    __syncthreads();

    // per-thread pixel: 16 -> 32 mix (float2 lanes -> v_pk_fma_f32) + nontemporal store
    float sv[16];
    #pragma unroll
    for (int k = 0; k < 4; ++k)
        *(f32x4*)(sv + 4*k) = *(const f32x4*)(st + tid*20 + 4*k);
    f32x2 acc[16];
    #pragma unroll
    for (int co2 = 0; co2 < 16; ++co2) {
        acc[co2][0] = cbs[2*co2];
        acc[co2][1] = cbs[2*co2 + 1];
    }
    #pragma unroll
    for (int c = 0; c < 16; ++c) {
        float v = sv[c];
        #pragma unroll
        for (int co2 = 0; co2 < 16; ++co2) {
            f32x2 w = *(const f32x2*)(w2s + c*32 + 2*co2);
            acc[co2] += w * v;
        }
    }
    int y = tid >> 4, px = tid & 15;
    float* ob = out + (size_t)b*32*HWP + (size_t)(h0 + y)*WW + w0 + px;
    #pragma unroll
    for (int co2 = 0; co2 < 16; ++co2) {
        __builtin_nontemporal_store(acc[co2][0], &ob[(size_t)(2*co2) * HWP]);
        __builtin_nontemporal_store(acc[co2][1], &ob[(size_t)(2*co2 + 1) * HWP]);
    }
}

extern "C" void kernel_launch(void* const* d_in, const int* in_sizes, int n_in,
                              void* d_out, int out_size, void* d_ws, size_t ws_size,
                              hipStream_t stream) {
    const float* x     = (const float*)d_in[0];
    const float* w1    = (const float*)d_in[1];  const float* b1 = (const float*)d_in[2];
    const float* w2    = (const float*)d_in[3];  const float* b2 = (const float*)d_in[4];
    const float* w3    = (const float*)d_in[5];  const float* b3 = (const float*)d_in[6];
    const float* w4    = (const float*)d_in[7];  const float* b4 = (const float*)d_in[8];
    const float* w5    = (const float*)d_in[9];  const float* b5 = (const float*)d_in[10];
    const float* gcn_w = (const float*)d_in[11]; const float* gcn_b = (const float*)d_in[12];
    const float* attn  = (const float*)d_in[13];
    const float* fw    = (const float*)d_in[14]; const float* fb = (const float*)d_in[15];
    float* ws  = (float*)d_ws;
    float* out = (float*)d_out;
    unsigned short* xbf = (unsigned short*)(ws + WS_XBF);

    // zero the sharded accumulators [WS_COLSH, WS_GSUMH end)
    hipMemsetAsync(ws + WS_COLSH, 0, (15872 - WS_COLSH) * sizeof(float), stream);
    transform_kernel<<<8*HH, 384, 0, stream>>>(x, ws, xbf);
    prep_kernel     <<<1, 256, 0, stream>>>(x, w1,b1,w2,b2,w3,b3,w4,b4,w5,b5,
                                            gcn_w, gcn_b, fw, fb, attn, ws);
    convfuse_kernel <<<4608, 256, 0, stream>>>(xbf, (const unsigned short*)(ws + WS_WBF), ws, out);
}